// Round 10
// baseline (787.641 us; speedup 1.0000x reference)
//
#include <hip/hip_runtime.h>
#include <hip/hip_bf16.h>
#include <stdint.h>

typedef float f32x4 __attribute__((ext_vector_type(4)));
typedef float fvec4 __attribute__((ext_vector_type(4)));
typedef short bf16x8 __attribute__((ext_vector_type(8)));

#define HALF_K 24576
#define NUMELK 49152
#define BATCH  8192
#define BM 256
#define BN 256
#define BK 64

#define VMCNT_I(n) asm volatile("s_waitcnt vmcnt(" #n ")" ::: "memory")
#define VMCNT(n) VMCNT_I(n)
#define LGKM0    asm volatile("s_waitcnt lgkmcnt(0)" ::: "memory")
#define SCHEDB   __builtin_amdgcn_sched_barrier(0)
#define SBAR     __builtin_amdgcn_s_barrier()

__device__ __forceinline__ short f2bf(float f) {
  __hip_bfloat16 h = __float2bfloat16(f);
  return __builtin_bit_cast(short, h);
}

__device__ __forceinline__ void gload_lds16(const short* g, short* l) {
  __builtin_amdgcn_global_load_lds(
      (const __attribute__((address_space(1))) unsigned*)g,
      (__attribute__((address_space(3))) unsigned*)l, 16, 0, 0);
}

// ---------------- prep: B pre-tiled + pre-swizzled bf16 ----------------
//   Bprep[KT*16384 + col*64 + ((kc ^ (col&7))<<3) + e],  k = KT*64 + kc*8 + e
__global__ __launch_bounds__(256)
void nnue_prep(const float* __restrict__ wW, const float* __restrict__ bW,
               short* __restrict__ Bprep) {
  int gid = blockIdx.x * 256 + threadIdx.x;   // grid 6144
  int KT  = gid >> 11;
  int rem = gid & 2047;
  int col = rem >> 3;
  int kc  = rem & 7;
  int kg  = KT * 64 + kc * 8;
  const float* src;
  if (col < 128) {
    src = wW + (size_t)col * NUMELK + kg;
  } else {
    int kk = (kg < HALF_K) ? (kg + HALF_K) : (kg - HALF_K);
    src = bW + (size_t)(col - 128) * NUMELK + kk;
  }
  fvec4 v0 = ((const fvec4*)src)[0];
  fvec4 v1 = ((const fvec4*)src)[1];
  bf16x8 o;
  o[0] = f2bf(v0[0]); o[1] = f2bf(v0[1]); o[2] = f2bf(v0[2]); o[3] = f2bf(v0[3]);
  o[4] = f2bf(v1[0]); o[5] = f2bf(v1[1]); o[6] = f2bf(v1[2]); o[7] = f2bf(v1[3]);
  *(bf16x8*)(Bprep + (size_t)KT * 16384 + col * 64 + ((kc ^ (col & 7)) << 3)) = o;
}

// ---------------- main GEMM: 8-phase fine-grained pipeline (m201 port) ----
// 256x256 tile, BK=64, 8 waves (2Mx4N), per-wave 128x64, acc[8][4].
// Outer iter i computes K-tiles T0=2i (A0/B0, phases 0-3), T1=2i+1 (A1/B1,
// phases 4-7), and stages: B1<-2i+1 (ph0 DMA), B0<-2i+2 (ph4 DMA),
// A1<-2i+1 (cvt+write ph0-3 from loads of prev ph4-7), A0<-2i+2 (ph4-7 from
// loads of ph0-3). vmcnt NEVER drains in steady state (6-10 in flight);
// DMA-retire vmcnt(8) sits before the closing barrier of ph3/ph7 so the
// opposite buffer is cross-wave-visible one phase-group before its readers.
__global__ __launch_bounds__(512, 2)
void nnue_gemm(const float* __restrict__ white, const float* __restrict__ black,
               const short* __restrict__ Bprep, float* __restrict__ partial,
               int kchunk, int S) {
  __shared__ short A0s[BM * BK];
  __shared__ short A1s[BM * BK];
  __shared__ short B0s[BN * BK];
  __shared__ short B1s[BN * BK];

  const int t    = threadIdx.x;
  const int lane = t & 63;
  const int wid  = t >> 6;

  const int bid = blockIdx.x;          // 32*S blocks
  const int xcd = bid & 7, bi = bid >> 3;
  const int xpk = 8 / S;               // S in {1,2,4,8}
  const int ks  = xcd / xpk;
  const int mt  = (xcd % xpk) * (32 / xpk) + bi;
  const int m0  = mt * BM;
  const int k0  = ks * kchunk;
  const int KT0 = k0 / BK;

  f32x4 acc[8][4];
  const f32x4 zero = {0.f, 0.f, 0.f, 0.f};
#pragma unroll
  for (int a = 0; a < 8; ++a)
#pragma unroll
    for (int b = 0; b < 4; ++b) acc[a][b] = zero;

  const int wm = wid >> 2, wn = wid & 3;
  const int l15 = lane & 15, l4 = lane >> 4;

  // A staging: thread owns row arow (0..255), half ah (32 floats)
  const int arow = t >> 1;
  const int ah   = t & 1;
  const size_t a_off = (size_t)(m0 + arow) * HALF_K + ah * 32;

  fvec4 pr[4][2];                      // rolling pairs: issue ph p, consume ph p+4

  auto issueApair = [&](int c, int kg) {
    const float* Af; int ka;
    if (kg < HALF_K) { Af = white; ka = kg; } else { Af = black; ka = kg - HALF_K; }
    const fvec4* src = (const fvec4*)(Af + a_off + ka);
    pr[c][0] = src[2 * c];
    pr[c][1] = src[2 * c + 1];
  };
  auto issueB = [&](short* dst, int KT) {      // 4 DMA instrs, wave quarter
    const short* src = Bprep + (size_t)KT * 16384 + wid * 2048 + lane * 8;
    short* d = dst + wid * 2048;
#pragma unroll
    for (int j = 0; j < 4; ++j)
      gload_lds16(src + j * 512, d + j * 512);
  };
  auto cvtWrite = [&](int c, short* Ad) {      // 1 ds_write_b128
    bf16x8 o;
    o[0] = f2bf(pr[c][0][0]); o[1] = f2bf(pr[c][0][1]);
    o[2] = f2bf(pr[c][0][2]); o[3] = f2bf(pr[c][0][3]);
    o[4] = f2bf(pr[c][1][0]); o[5] = f2bf(pr[c][1][1]);
    o[6] = f2bf(pr[c][1][2]); o[7] = f2bf(pr[c][1][3]);
    *(bf16x8*)&Ad[arow * 64 + (((ah * 4 + c) ^ (arow & 7)) << 3)] = o;
  };

  // fragment addressing (row&7 == l15&7 for all mf; col&7 == l15&7)
  const int swz0 = ((l4)     ^ (l15 & 7)) << 3;   // s=0 (kc = l4)
  const int swz1 = ((4 + l4) ^ (l15 & 7)) << 3;   // s=1 (kc = 4+l4)
  const int aRowBase = (wm * 128 + l15) * 64;     // + mf*1024
  const int bColBase = (wn * 64 + l15) * 64;      // + (2h+j)*1024

  bf16x8 af[8], b0f, b1f;
  auto readAF = [&](const short* Ab, int swz) {
#pragma unroll
    for (int mf = 0; mf < 8; ++mf)
      af[mf] = *(const bf16x8*)&Ab[aRowBase + mf * 1024 + swz];
  };
  auto readBF = [&](const short* Bb, int swz, int h) {
    b0f = *(const bf16x8*)&Bb[bColBase + (2 * h) * 1024 + swz];
    b1f = *(const bf16x8*)&Bb[bColBase + (2 * h + 1) * 1024 + swz];
  };
  auto mfma16 = [&](int h) {
#pragma unroll
    for (int mf = 0; mf < 8; ++mf) {
      acc[mf][2 * h]     = __builtin_amdgcn_mfma_f32_16x16x32_bf16(af[mf], b0f, acc[mf][2 * h], 0, 0, 0);
      acc[mf][2 * h + 1] = __builtin_amdgcn_mfma_f32_16x16x32_bf16(af[mf], b1f, acc[mf][2 * h + 1], 0, 0, 0);
    }
  };

#define PH_TAIL(H) SCHEDB; SBAR; LGKM0; SCHEDB; \
  __builtin_amdgcn_s_setprio(1); mfma16(H); __builtin_amdgcn_s_setprio(0); SCHEDB

  const int niter = kchunk / BK;       // even, >= 2
  const int nI2   = niter / 2;

  // ---- prologue: A0<-tile0 (direct), B0-DMA<-tile0, pairs<-tile1
#pragma unroll
  for (int c = 0; c < 4; ++c) issueApair(c, k0);
  VMCNT(0);
#pragma unroll
  for (int c = 0; c < 4; ++c) cvtWrite(c, A0s);
  issueB(B0s, KT0);                    // D4 (oldest in queue)
#pragma unroll
  for (int c = 0; c < 4; ++c) issueApair(c, k0 + BK);   // tile 1
  VMCNT(8);                            // retire B0 DMAs (cross-wave: before bar)
  LGKM0;
  SBAR;

  // ---- main loop: iters 0..nI2-2 (full staging)
  for (int i = 0; i < nI2 - 1; ++i) {
    const int tb1 = 2 * i + 1;         // B1 <- this iter's T1
    const int ta2 = k0 + (2 * i + 2) * BK;   // A-loads ph0-3
    const int ta3 = k0 + (2 * i + 3) * BK;   // A-loads ph4-7

    // ph0: T0,s0,h0
    VMCNT(6); SCHEDB;
    cvtWrite(0, A1s);
    issueB(B1s, KT0 + tb1);
    issueApair(0, ta2);
    readAF(A0s, swz0); readBF(B0s, swz0, 0);
    PH_TAIL(0); SBAR;
    // ph1: T0,s0,h1
    VMCNT(10); SCHEDB;
    cvtWrite(1, A1s);
    issueApair(1, ta2);
    readBF(B0s, swz0, 1);
    PH_TAIL(1); SBAR;
    // ph2: T0,s1,h0
    VMCNT(10); SCHEDB;
    cvtWrite(2, A1s);
    issueApair(2, ta2);
    readAF(A0s, swz1); readBF(B0s, swz1, 0);
    PH_TAIL(0); SBAR;
    // ph3: T0,s1,h1  (end: retire ph0's B1-DMAs before closing bar)
    VMCNT(10); SCHEDB;
    cvtWrite(3, A1s);
    issueApair(3, ta2);
    readBF(B0s, swz1, 1);
    PH_TAIL(1);
    VMCNT(8); SBAR;
    // ph4: T1,s0,h0
    VMCNT(6); SCHEDB;
    cvtWrite(0, A0s);
    issueB(B0s, KT0 + 2 * i + 2);
    issueApair(0, ta3);
    readAF(A1s, swz0); readBF(B1s, swz0, 0);
    PH_TAIL(0); SBAR;
    // ph5: T1,s0,h1
    VMCNT(10); SCHEDB;
    cvtWrite(1, A0s);
    issueApair(1, ta3);
    readBF(B1s, swz0, 1);
    PH_TAIL(1); SBAR;
    // ph6: T1,s1,h0
    VMCNT(10); SCHEDB;
    cvtWrite(2, A0s);
    issueApair(2, ta3);
    readAF(A1s, swz1); readBF(B1s, swz1, 0);
    PH_TAIL(0); SBAR;
    // ph7: T1,s1,h1  (end: retire ph4's B0-DMAs before closing bar)
    VMCNT(10); SCHEDB;
    cvtWrite(3, A0s);
    issueApair(3, ta3);
    readBF(B1s, swz1, 1);
    PH_TAIL(1);
    VMCNT(8); SBAR;
  }

  // ---- final iter: tiles niter-2 (A0/B0 ready), niter-1 (stage A1/B1 now)
  {
    issueB(B1s, KT0 + niter - 1);      // D4 newest
    VMCNT(4);                          // retire all 4 pairs (tile niter-1)
#pragma unroll
    for (int c = 0; c < 4; ++c) cvtWrite(c, A1s);
    VMCNT(0);                          // B1 DMAs landed (before bar: cross-wave)
    LGKM0;
    SBAR;
    // T0 from A0/B0
    readAF(A0s, swz0); readBF(B0s, swz0, 0); LGKM0; SCHEDB; mfma16(0);
    readBF(B0s, swz0, 1); LGKM0; SCHEDB; mfma16(1);
    readAF(A0s, swz1); readBF(B0s, swz1, 0); LGKM0; SCHEDB; mfma16(0);
    readBF(B0s, swz1, 1); LGKM0; SCHEDB; mfma16(1);
    // T1 from A1/B1
    readAF(A1s, swz0); readBF(B1s, swz0, 0); LGKM0; SCHEDB; mfma16(0);
    readBF(B1s, swz0, 1); LGKM0; SCHEDB; mfma16(1);
    readAF(A1s, swz1); readBF(B1s, swz1, 0); LGKM0; SCHEDB; mfma16(0);
    readBF(B1s, swz1, 1); LGKM0; SCHEDB; mfma16(1);
  }
#undef PH_TAIL

  // ---- epilogue: C/D layout col=lane&15, row=(lane>>4)*4+r   [m89]
  float* P = partial + ((size_t)ks * BATCH + m0) * 256;
#pragma unroll
  for (int mf = 0; mf < 8; ++mf) {
    int row = wm * 128 + mf * 16 + l4 * 4;
#pragma unroll
    for (int nf = 0; nf < 4; ++nf) {
      int col = wn * 64 + nf * 16 + l15;
#pragma unroll
      for (int rr = 0; rr < 4; ++rr)
        P[(size_t)(row + rr) * 256 + col] = acc[mf][nf][rr];
    }
  }
}

// ---------------- tail: partial-reduce + pov mix + relu + fc0..fc3 ----------------
__global__ __launch_bounds__(256)
void nnue_tail(const float* __restrict__ partial, int S,
               const float* __restrict__ pov,
               const float* __restrict__ waffb, const float* __restrict__ baffb,
               const float* __restrict__ fc0W, const float* __restrict__ fc0b,
               const float* __restrict__ fc1W, const float* __restrict__ fc1b,
               const float* __restrict__ fc2W, const float* __restrict__ fc2b,
               const float* __restrict__ fc3W, const float* __restrict__ fc3b,
               float* __restrict__ out) {
  __shared__ float w0s[32 * 256];   // stored at [(j<<8) | ((k+j)&255)]
  __shared__ float w1s[32 * 32];    // [(j<<5) | ((k+j)&31)]
  __shared__ float w2s[32 * 64];    // [(j<<6) | ((k+j)&63)]
  __shared__ float w3s[96];
  __shared__ float b0s[32], b1s[32], b2s[32];
  __shared__ float base_s[4][256];
  __shared__ float b3s;

  const int t = threadIdx.x;
  for (int i = t; i < 8192; i += 256) { int j = i >> 8, k = i & 255; w0s[(j << 8) | ((k + j) & 255)] = fc0W[i]; }
  for (int i = t; i < 1024; i += 256) { int j = i >> 5, k = i & 31;  w1s[(j << 5) | ((k + j) & 31)]  = fc1W[i]; }
  for (int i = t; i < 2048; i += 256) { int j = i >> 6, k = i & 63;  w2s[(j << 6) | ((k + j) & 63)]  = fc2W[i]; }
  if (t < 96) w3s[t] = fc3W[t];
  if (t < 32) { b0s[t] = fc0b[t]; b1s[t] = fc1b[t]; b2s[t] = fc2b[t]; }
  if (t == 0) b3s = fc3b[0];
  __syncthreads();

  const int wid = t >> 6, lane = t & 63;
  const int m = blockIdx.x * 4 + wid;
  const float pv = pov[m];

  float val[4];
  {
    const float* p = partial + (size_t)m * 256 + lane * 4;
    fvec4 a = *(const fvec4*)p;
    for (int s = 1; s < S; ++s) a += *(const fvec4*)(p + (size_t)s * BATCH * 256);
    const int c0 = lane * 4;
#pragma unroll
    for (int j = 0; j < 4; ++j) {
      int c = c0 + j;
      float bias = (c < 128) ? waffb[c] : baffb[c - 128];
      val[j] = a[j] + bias;
    }
  }
#pragma unroll
  for (int j = 0; j < 4; ++j) {
    float other = __shfl(val[j], lane ^ 32, 64);
    if (lane < 32) {
      int c = lane * 4 + j;
      float w = val[j], b = other;
      base_s[wid][c]       = fmaxf(pv * w + (1.f - pv) * b, 0.f);
      base_s[wid][c + 128] = fmaxf(pv * b + (1.f - pv) * w, 0.f);
    }
  }
  __syncthreads();

  const int j = lane & 31, half = lane >> 5;
  const float* bs = &base_s[wid][0];

  float s0 = 0.f;
  for (int k = 0; k < 128; ++k) {
    int kk = half * 128 + k;
    s0 += bs[kk] * w0s[(j << 8) | ((kk + j) & 255)];
  }
  s0 += __shfl(s0, lane ^ 32, 64);
  float x0 = fmaxf(s0 + b0s[j], 0.f);

  float s1 = 0.f;
  for (int k = 0; k < 32; ++k)
    s1 += __shfl(x0, k, 64) * w1s[(j << 5) | ((k + j) & 31)];
  float x1 = fmaxf(s1 + b1s[j], 0.f);

  float s2 = 0.f;
  for (int k = 0; k < 32; ++k) {
    s2 += __shfl(x0, k, 64) * w2s[(j << 6) | ((k + j) & 63)];
    s2 += __shfl(x1, k, 64) * w2s[(j << 6) | ((k + 32 + j) & 63)];
  }
  float x2 = fmaxf(s2 + b2s[j], 0.f);

  float s3 = 0.f;
  for (int k = 0; k < 32; ++k) {
    s3 += __shfl(x0, k, 64) * w3s[k];
    s3 += __shfl(x1, k, 64) * w3s[32 + k];
    s3 += __shfl(x2, k, 64) * w3s[64 + k];
  }
  if (lane == 0) out[m] = s3 + b3s;
}

extern "C" void kernel_launch(void* const* d_in, const int* in_sizes, int n_in,
                              void* d_out, int out_size, void* d_ws, size_t ws_size,
                              hipStream_t stream) {
  const float* pov   = (const float*)d_in[0];
  const float* white = (const float*)d_in[1];
  const float* black = (const float*)d_in[2];
  const float* wW    = (const float*)d_in[3];
  const float* wb    = (const float*)d_in[4];
  const float* bW    = (const float*)d_in[5];
  const float* bb    = (const float*)d_in[6];
  const float* fc0W  = (const float*)d_in[7];
  const float* fc0b  = (const float*)d_in[8];
  const float* fc1W  = (const float*)d_in[9];
  const float* fc1b  = (const float*)d_in[10];
  const float* fc2W  = (const float*)d_in[11];
  const float* fc2b  = (const float*)d_in[12];
  const float* fc3W  = (const float*)d_in[13];
  const float* fc3b  = (const float*)d_in[14];
  float* out = (float*)d_out;

  short* Bprep = (short*)d_ws;
  const size_t BWS_BYTES = (size_t)256 * NUMELK * 2;      // 25,165,824
  float* partial = (float*)((char*)d_ws + BWS_BYTES);
  const size_t PART1 = (size_t)BATCH * 256 * 4;           // 8,388,608

  int S = 8;                                              // 256 blocks = 1/CU
  if (ws_size < BWS_BYTES + 8 * PART1) S = 4;
  if (ws_size < BWS_BYTES + 4 * PART1) S = 2;
  if (ws_size < BWS_BYTES + 2 * PART1) S = 1;

  nnue_prep<<<dim3(6144), 256, 0, stream>>>(wW, bW, Bprep);
  nnue_gemm<<<dim3(32 * S), 512, 0, stream>>>(white, black, Bprep, partial, NUMELK / S, S);
  nnue_tail<<<dim3(BATCH / 4), 256, 0, stream>>>(partial, S, pov, wb, bb,
      fc0W, fc0b, fc1W, fc1b, fc2W, fc2b, fc3W, fc3b, out);
}

// Round 11
// 442.745 us; speedup vs baseline: 1.7790x; 1.7790x over previous
//
#include <hip/hip_runtime.h>
#include <hip/hip_bf16.h>
#include <stdint.h>

typedef float f32x4 __attribute__((ext_vector_type(4)));
typedef float fvec4 __attribute__((ext_vector_type(4)));
typedef short bf16x8 __attribute__((ext_vector_type(8)));

#define HALF_K 24576
#define NUMELK 49152
#define BATCH  8192
#define BM 256
#define BN 256
#define BK 64

#define VMCNT_I(n) asm volatile("s_waitcnt vmcnt(" #n ")" ::: "memory")
#define VMCNT(n) VMCNT_I(n)
#define SCHEDB   __builtin_amdgcn_sched_barrier(0)
#define SBAR     __builtin_amdgcn_s_barrier()

__device__ __forceinline__ short f2bf(float f) {
  __hip_bfloat16 h = __float2bfloat16(f);
  return __builtin_bit_cast(short, h);
}

__device__ __forceinline__ void gload_lds16(const short* g, short* l) {
  __builtin_amdgcn_global_load_lds(
      (const __attribute__((address_space(1))) unsigned*)g,
      (__attribute__((address_space(3))) unsigned*)l, 16, 0, 0);
}

// ---------------- prep: B pre-tiled + pre-swizzled bf16 ----------------
//   Bprep[KT*16384 + col*64 + ((kc ^ (col&7))<<3) + e],  k = KT*64 + kc*8 + e
__global__ __launch_bounds__(256)
void nnue_prep(const float* __restrict__ wW, const float* __restrict__ bW,
               short* __restrict__ Bprep) {
  int gid = blockIdx.x * 256 + threadIdx.x;   // grid 6144
  int KT  = gid >> 11;
  int rem = gid & 2047;
  int col = rem >> 3;
  int kc  = rem & 7;
  int kg  = KT * 64 + kc * 8;
  const float* src;
  if (col < 128) {
    src = wW + (size_t)col * NUMELK + kg;
  } else {
    int kk = (kg < HALF_K) ? (kg + HALF_K) : (kg - HALF_K);
    src = bW + (size_t)(col - 128) * NUMELK + kk;
  }
  fvec4 v0 = ((const fvec4*)src)[0];
  fvec4 v1 = ((const fvec4*)src)[1];
  bf16x8 o;
  o[0] = f2bf(v0[0]); o[1] = f2bf(v0[1]); o[2] = f2bf(v0[2]); o[3] = f2bf(v0[3]);
  o[4] = f2bf(v1[0]); o[5] = f2bf(v1[1]); o[6] = f2bf(v1[2]); o[7] = f2bf(v1[3]);
  *(bf16x8*)(Bprep + (size_t)KT * 16384 + col * 64 + ((kc ^ (col & 7)) << 3)) = o;
}

// ---------------- main GEMM: [8192 x 49152] x [49152 x 256] ----------------
// Wave-private-A structure: 8 waves, wave w owns output rows m0+32w..+31 and
// ALL 256 cols (acc[2][16]). A goes global->reg->cvt->MFMA directly (no LDS,
// no barriers on the 1.6GB stream); each load-pair covers 16 rows x 128
// contiguous bytes -> full 64B-line consumption (R10's over-fetch fixed).
// B (L2-resident, pre-swizzled) double-buffered in LDS via global_load_lds;
// ONE raw s_barrier + counted vmcnt per K-tile; vmcnt never drains (>=8 in
// flight steady-state).
__global__ __launch_bounds__(512, 2)
void nnue_gemm(const float* __restrict__ white, const float* __restrict__ black,
               const short* __restrict__ Bprep, float* __restrict__ partial,
               int kchunk, int S) {
  __shared__ short B0s[BN * BK];   // 32 KB
  __shared__ short B1s[BN * BK];   // 32 KB

  const int t    = threadIdx.x;
  const int lane = t & 63;
  const int w    = t >> 6;             // wave 0..7: rows m0+32w..+31

  const int bid = blockIdx.x;          // 32*S blocks
  const int xcd = bid & 7, bi = bid >> 3;
  const int xpk = 8 / S;               // S in {1,2,4,8}
  const int ks  = xcd / xpk;
  const int mt  = (xcd % xpk) * (32 / xpk) + bi;
  const int m0  = mt * BM;
  const int k0  = ks * kchunk;
  const int KT0 = k0 / BK;

  f32x4 acc[2][16];
  const f32x4 zero = {0.f, 0.f, 0.f, 0.f};
#pragma unroll
  for (int a = 0; a < 2; ++a)
#pragma unroll
    for (int b = 0; b < 16; ++b) acc[a][b] = zero;

  const int l15 = lane & 15, l4 = lane >> 4;

  // A: lane reads row (m0+32w+l15 [+16 for mf=1]), floats [kg + s*32 + l4*8, +8)
  const size_t arow_off = (size_t)(m0 + w * 32 + l15) * HALF_K + l4 * 8;

  // issue 8 dwordx4 for one K-tile into va[8]: va[mf*4 + s*2 + p]
  auto issueA = [&](fvec4* va, int kg) {
    const float* Af; int ka;
    if (kg < HALF_K) { Af = white; ka = kg; } else { Af = black; ka = kg - HALF_K; }
    const float* base = Af + arow_off + ka;
#pragma unroll
    for (int mf = 0; mf < 2; ++mf)
#pragma unroll
      for (int s = 0; s < 2; ++s) {
        const fvec4* p = (const fvec4*)(base + (size_t)mf * 16 * HALF_K + s * 32);
        va[mf * 4 + s * 2]     = p[0];
        va[mf * 4 + s * 2 + 1] = p[1];
      }
  };

  auto issueB = [&](short* dst, int KT) {      // 4 DMA instrs per wave
    const short* src = Bprep + (size_t)KT * 16384 + w * 2048 + lane * 8;
    short* d = dst + w * 2048;
#pragma unroll
    for (int j = 0; j < 4; ++j)
      gload_lds16(src + j * 512, d + j * 512);
  };

  auto compute = [&](const short* Bb, const fvec4* va) {
#pragma unroll
    for (int s = 0; s < 2; ++s) {
      bf16x8 af[2];
#pragma unroll
      for (int mf = 0; mf < 2; ++mf) {
        const fvec4 lo = va[mf * 4 + s * 2];
        const fvec4 hi = va[mf * 4 + s * 2 + 1];
        af[mf][0] = f2bf(lo[0]); af[mf][1] = f2bf(lo[1]);
        af[mf][2] = f2bf(lo[2]); af[mf][3] = f2bf(lo[3]);
        af[mf][4] = f2bf(hi[0]); af[mf][5] = f2bf(hi[1]);
        af[mf][6] = f2bf(hi[2]); af[mf][7] = f2bf(hi[3]);
      }
      const int kc = s * 4 + l4;
#pragma unroll
      for (int nf = 0; nf < 16; ++nf) {
        int col = nf * 16 + l15;
        bf16x8 bf = *(const bf16x8*)&Bb[col * 64 + ((kc ^ (col & 7)) << 3)];
        acc[0][nf] = __builtin_amdgcn_mfma_f32_16x16x32_bf16(af[0], bf, acc[0][nf], 0, 0, 0);
        acc[1][nf] = __builtin_amdgcn_mfma_f32_16x16x32_bf16(af[1], bf, acc[1][nf], 0, 0, 0);
      }
    }
  };

  const int niter = kchunk / BK;       // even (96 at S=8)

  fvec4 vaA[8], vaB[8];

  // prologue: tile 0 -> B0s + vaA
  issueB(B0s, KT0);                    // queue [B4]
  issueA(vaA, k0);                     // queue [B4, A8]
  VMCNT(8); SCHEDB;                    // own B0 DMAs retired
  SBAR; SCHEDB;                        // all waves' B0 DMAs visible

  for (int i = 0; i < niter; i += 2) {
    // even tile i: B0s + vaA; stage i+1 -> B1s + vaB
    if (i + 1 < niter) {
      issueB(B1s, KT0 + i + 1);
      issueA(vaB, k0 + (i + 1) * BK);
    }
    SCHEDB;
    compute(B0s, vaA);                 // cvt auto-waits vaA (issued 1 tile ago)
    VMCNT(8); SCHEDB;                  // retire B1 DMAs, keep vaB in flight
    SBAR; SCHEDB;

    if (i + 1 < niter) {
      // odd tile i+1: B1s + vaB; stage i+2 -> B0s + vaA
      if (i + 2 < niter) {
        issueB(B0s, KT0 + i + 2);
        issueA(vaA, k0 + (i + 2) * BK);
      }
      SCHEDB;
      compute(B1s, vaB);
      VMCNT(8); SCHEDB;
      SBAR; SCHEDB;
    }
  }

  // ---- epilogue: C/D layout col=lane&15, row=(lane>>4)*4+r   [m89]
  float* P = partial + ((size_t)ks * BATCH + m0) * 256;
#pragma unroll
  for (int mf = 0; mf < 2; ++mf) {
    int row = w * 32 + mf * 16 + l4 * 4;
#pragma unroll
    for (int nf = 0; nf < 16; ++nf) {
      int col = nf * 16 + l15;
#pragma unroll
      for (int rr = 0; rr < 4; ++rr)
        P[(size_t)(row + rr) * 256 + col] = acc[mf][nf][rr];
    }
  }
}

// ---------------- tail: partial-reduce + pov mix + relu + fc0..fc3 ----------------
__global__ __launch_bounds__(256)
void nnue_tail(const float* __restrict__ partial, int S,
               const float* __restrict__ pov,
               const float* __restrict__ waffb, const float* __restrict__ baffb,
               const float* __restrict__ fc0W, const float* __restrict__ fc0b,
               const float* __restrict__ fc1W, const float* __restrict__ fc1b,
               const float* __restrict__ fc2W, const float* __restrict__ fc2b,
               const float* __restrict__ fc3W, const float* __restrict__ fc3b,
               float* __restrict__ out) {
  __shared__ float w0s[32 * 256];   // stored at [(j<<8) | ((k+j)&255)]
  __shared__ float w1s[32 * 32];    // [(j<<5) | ((k+j)&31)]
  __shared__ float w2s[32 * 64];    // [(j<<6) | ((k+j)&63)]
  __shared__ float w3s[96];
  __shared__ float b0s[32], b1s[32], b2s[32];
  __shared__ float base_s[4][256];
  __shared__ float b3s;

  const int t = threadIdx.x;
  for (int i = t; i < 8192; i += 256) { int j = i >> 8, k = i & 255; w0s[(j << 8) | ((k + j) & 255)] = fc0W[i]; }
  for (int i = t; i < 1024; i += 256) { int j = i >> 5, k = i & 31;  w1s[(j << 5) | ((k + j) & 31)]  = fc1W[i]; }
  for (int i = t; i < 2048; i += 256) { int j = i >> 6, k = i & 63;  w2s[(j << 6) | ((k + j) & 63)]  = fc2W[i]; }
  if (t < 96) w3s[t] = fc3W[t];
  if (t < 32) { b0s[t] = fc0b[t]; b1s[t] = fc1b[t]; b2s[t] = fc2b[t]; }
  if (t == 0) b3s = fc3b[0];
  __syncthreads();

  const int wid = t >> 6, lane = t & 63;
  const int m = blockIdx.x * 4 + wid;
  const float pv = pov[m];

  float val[4];
  {
    const float* p = partial + (size_t)m * 256 + lane * 4;
    fvec4 a = *(const fvec4*)p;
    for (int s = 1; s < S; ++s) a += *(const fvec4*)(p + (size_t)s * BATCH * 256);
    const int c0 = lane * 4;
#pragma unroll
    for (int j = 0; j < 4; ++j) {
      int c = c0 + j;
      float bias = (c < 128) ? waffb[c] : baffb[c - 128];
      val[j] = a[j] + bias;
    }
  }
#pragma unroll
  for (int j = 0; j < 4; ++j) {
    float other = __shfl(val[j], lane ^ 32, 64);
    if (lane < 32) {
      int c = lane * 4 + j;
      float w = val[j], b = other;
      base_s[wid][c]       = fmaxf(pv * w + (1.f - pv) * b, 0.f);
      base_s[wid][c + 128] = fmaxf(pv * b + (1.f - pv) * w, 0.f);
    }
  }
  __syncthreads();

  const int j = lane & 31, half = lane >> 5;
  const float* bs = &base_s[wid][0];

  float s0 = 0.f;
  for (int k = 0; k < 128; ++k) {
    int kk = half * 128 + k;
    s0 += bs[kk] * w0s[(j << 8) | ((kk + j) & 255)];
  }
  s0 += __shfl(s0, lane ^ 32, 64);
  float x0 = fmaxf(s0 + b0s[j], 0.f);

  float s1 = 0.f;
  for (int k = 0; k < 32; ++k)
    s1 += __shfl(x0, k, 64) * w1s[(j << 5) | ((k + j) & 31)];
  float x1 = fmaxf(s1 + b1s[j], 0.f);

  float s2 = 0.f;
  for (int k = 0; k < 32; ++k) {
    s2 += __shfl(x0, k, 64) * w2s[(j << 6) | ((k + j) & 63)];
    s2 += __shfl(x1, k, 64) * w2s[(j << 6) | ((k + 32 + j) & 63)];
  }
  float x2 = fmaxf(s2 + b2s[j], 0.f);

  float s3 = 0.f;
  for (int k = 0; k < 32; ++k) {
    s3 += __shfl(x0, k, 64) * w3s[k];
    s3 += __shfl(x1, k, 64) * w3s[32 + k];
    s3 += __shfl(x2, k, 64) * w3s[64 + k];
  }
  if (lane == 0) out[m] = s3 + b3s;
}

extern "C" void kernel_launch(void* const* d_in, const int* in_sizes, int n_in,
                              void* d_out, int out_size, void* d_ws, size_t ws_size,
                              hipStream_t stream) {
  const float* pov   = (const float*)d_in[0];
  const float* white = (const float*)d_in[1];
  const float* black = (const float*)d_in[2];
  const float* wW    = (const float*)d_in[3];
  const float* wb    = (const float*)d_in[4];
  const float* bW    = (const float*)d_in[5];
  const float* bb    = (const float*)d_in[6];
  const float* fc0W  = (const float*)d_in[7];
  const float* fc0b  = (const float*)d_in[8];
  const float* fc1W  = (const float*)d_in[9];
  const float* fc1b  = (const float*)d_in[10];
  const float* fc2W  = (const float*)d_in[11];
  const float* fc2b  = (const float*)d_in[12];
  const float* fc3W  = (const float*)d_in[13];
  const float* fc3b  = (const float*)d_in[14];
  float* out = (float*)d_out;

  short* Bprep = (short*)d_ws;
  const size_t BWS_BYTES = (size_t)256 * NUMELK * 2;      // 25,165,824
  float* partial = (float*)((char*)d_ws + BWS_BYTES);
  const size_t PART1 = (size_t)BATCH * 256 * 4;           // 8,388,608

  int S = 8;                                              // 256 blocks = 1/CU
  if (ws_size < BWS_BYTES + 8 * PART1) S = 4;
  if (ws_size < BWS_BYTES + 4 * PART1) S = 2;
  if (ws_size < BWS_BYTES + 2 * PART1) S = 1;

  nnue_prep<<<dim3(6144), 256, 0, stream>>>(wW, bW, Bprep);
  nnue_gemm<<<dim3(32 * S), 512, 0, stream>>>(white, black, Bprep, partial, NUMELK / S, S);
  nnue_tail<<<dim3(BATCH / 4), 256, 0, stream>>>(partial, S, pov, wb, bb,
      fc0W, fc0b, fc1W, fc1b, fc2W, fc2b, fc3W, fc3b, out);
}